// Round 11
// baseline (276.231 us; speedup 1.0000x reference)
//
#include <hip/hip_runtime.h>
#include <hip/hip_bf16.h>

#define BB 64
#define TT 512
#define FF 1024
#define KK 64

typedef unsigned char uchar;

// ---------------- Emission GEMM (round-1 version, measured ~83-88us, 5x) ----------------
#define BM 64
#define BF 64
#define LDA 68

__global__ __launch_bounds__(256)
void emission_kernel(const float* __restrict__ X, const float* __restrict__ W,
                     const float* __restrict__ bias, float* __restrict__ em)
{
    __shared__ float As[BF][LDA];
    __shared__ float Bs[BF][LDA];
    const int tid = threadIdx.x;
    const int row0 = blockIdx.x * BM;
    const int tm = tid & 15;
    const int tn = tid >> 4;
    const int lq = tid & 15;
    const int lr = tid >> 4;

    float acc[4][4];
#pragma unroll
    for (int i = 0; i < 4; ++i)
#pragma unroll
        for (int jj = 0; jj < 4; ++jj) acc[i][jj] = 0.f;

    for (int f0 = 0; f0 < FF; f0 += BF) {
#pragma unroll
        for (int p = 0; p < 4; ++p) {
            const int r = p * 16 + lr;
            float4 a = *(const float4*)(X + (size_t)(row0 + r) * FF + f0 + lq * 4);
            As[lq * 4 + 0][r] = a.x;
            As[lq * 4 + 1][r] = a.y;
            As[lq * 4 + 2][r] = a.z;
            As[lq * 4 + 3][r] = a.w;
            float4 w = *(const float4*)(W + (size_t)r * FF + f0 + lq * 4);
            Bs[lq * 4 + 0][r] = w.x;
            Bs[lq * 4 + 1][r] = w.y;
            Bs[lq * 4 + 2][r] = w.z;
            Bs[lq * 4 + 3][r] = w.w;
        }
        __syncthreads();
#pragma unroll
        for (int f = 0; f < BF; ++f) {
            float4 a = *(const float4*)&As[f][tm * 4];
            float4 b = *(const float4*)&Bs[f][tn * 4];
            acc[0][0] += a.x * b.x; acc[0][1] += a.x * b.y; acc[0][2] += a.x * b.z; acc[0][3] += a.x * b.w;
            acc[1][0] += a.y * b.x; acc[1][1] += a.y * b.y; acc[1][2] += a.y * b.z; acc[1][3] += a.y * b.w;
            acc[2][0] += a.z * b.x; acc[2][1] += a.z * b.y; acc[2][2] += a.z * b.z; acc[2][3] += a.z * b.w;
            acc[3][0] += a.w * b.x; acc[3][1] += a.w * b.y; acc[3][2] += a.w * b.z; acc[3][3] += a.w * b.w;
        }
        __syncthreads();
    }

    const float4 b4 = *(const float4*)(bias + tn * 4);
#pragma unroll
    for (int i = 0; i < 4; ++i) {
        float4 o;
        o.x = acc[i][0] + b4.x;
        o.y = acc[i][1] + b4.y;
        o.z = acc[i][2] + b4.z;
        o.w = acc[i][3] + b4.w;
        *(float4*)(em + (size_t)(row0 + tm * 4 + i) * KK + tn * 4) = o;
    }
}

// ---------------- Forward: value-only recurrence, 1 wave/seq ----------------
// r10 post-mortem: VGPR=48 with the pin -> tc[] lives in AGPRs (unified file),
// costing ~64 v_accvgpr_read/step. Root cause: the backend's occupancy
// heuristic, which __launch_bounds__(64,1) (a MINIMUM) does not pin.
// Fix: amdgpu_waves_per_eu(1,1) pins occupancy at exactly 1 wave/EU ->
// register budget 512, no benefit to small footprint -> tc in arch VGPRs.
#define RLANE(I) __uint_as_float((unsigned)__builtin_amdgcn_readlane((int)__float_as_uint(score), (I)))

#define VSTEP(EV, TIDX) do {                                                   \
    float m_;                                                                  \
    _Pragma("unroll")                                                          \
    for (int c = 0; c < 8; ++c) {                                              \
        const float v0 = RLANE(c * 8 + 0) + tc[c * 8 + 0];                     \
        const float v1 = RLANE(c * 8 + 1) + tc[c * 8 + 1];                     \
        const float v2 = RLANE(c * 8 + 2) + tc[c * 8 + 2];                     \
        const float v3 = RLANE(c * 8 + 3) + tc[c * 8 + 3];                     \
        const float v4 = RLANE(c * 8 + 4) + tc[c * 8 + 4];                     \
        const float v5 = RLANE(c * 8 + 5) + tc[c * 8 + 5];                     \
        const float v6 = RLANE(c * 8 + 6) + tc[c * 8 + 6];                     \
        const float v7 = RLANE(c * 8 + 7) + tc[c * 8 + 7];                     \
        const float ma = fmaxf(fmaxf(v0, v1), v2);   /* v_max3 */              \
        const float mb = fmaxf(fmaxf(v3, v4), v5);   /* v_max3 */              \
        const float mc = fmaxf(fmaxf(v6, v7), ma);   /* v_max3 */              \
        const float w_ = fmaxf(mb, mc);                                        \
        m_ = (c == 0) ? w_ : fmaxf(m_, w_);                                    \
    }                                                                          \
    score = m_ + (EV);                                                         \
    sb[(size_t)(TIDX) * KK + j] = score;                                       \
} while (0)

__global__ __launch_bounds__(64)
__attribute__((amdgpu_waves_per_eu(1, 1)))
void viterbi_fwd(const float* __restrict__ em, const void* __restrict__ maskp,
                 const float* __restrict__ startT, const float* __restrict__ endT,
                 const float* __restrict__ trans, float* __restrict__ shist,
                 int* __restrict__ btarr)
{
    const int b = blockIdx.x;
    const int j = threadIdx.x;

    const uchar* m8 = (const uchar*)maskp;
    const int* m32 = (const int*)maskp;
    const bool u8m = (m8[1] != 0);

    // ---- length precompute (mask is monotone: true for t < len) ----
    int myc;
    if (u8m) {
        const uint2 mv = *(const uint2*)(m8 + (size_t)b * TT + j * 8);
        const unsigned s4 = (mv.x & 0x01010101u) + (mv.y & 0x01010101u);
        myc = (int)((s4 * 0x01010101u) >> 24);
    } else {
        const int* mp = m32 + (size_t)b * TT + j * 8;
        const int4 a = *(const int4*)mp;
        const int4 c = *(const int4*)(mp + 4);
        myc = (a.x != 0) + (a.y != 0) + (a.z != 0) + (a.w != 0)
            + (c.x != 0) + (c.y != 0) + (c.z != 0) + (c.w != 0);
    }
#pragma unroll
    for (int o = 1; o < 64; o <<= 1) myc += __shfl_xor(myc, o, 64);
    const int len = myc;   // valid timesteps; loop runs t = 1..len-1

    float tc[KK];
#pragma unroll
    for (int i = 0; i < KK; ++i) tc[i] = trans[i * KK + j];
    // PIN: opaque asm result -> loads cannot be rematerialized in-loop
#pragma unroll
    for (int i = 0; i < KK; ++i) asm volatile("" : "+v"(tc[i]));

    const float* emb = em + (size_t)b * TT * KK;
    float* sb = shist + (size_t)b * TT * KK;

    float score = startT[j] + emb[j];   // t = 0
    sb[j] = score;

    // named prefetch slots: eA..eD hold e for t, t+1, t+2, t+3
    float eA = emb[1 * KK + j];
    float eB = emb[2 * KK + j];
    float eC = emb[3 * KK + j];
    float eD = emb[4 * KK + j];

    int t = 1;
    for (; t + 3 < len; t += 4) {
        VSTEP(eA, t);     eA = emb[(size_t)((t + 4 < TT) ? t + 4 : TT - 1) * KK + j];
        VSTEP(eB, t + 1); eB = emb[(size_t)((t + 5 < TT) ? t + 5 : TT - 1) * KK + j];
        VSTEP(eC, t + 2); eC = emb[(size_t)((t + 6 < TT) ? t + 6 : TT - 1) * KK + j];
        VSTEP(eD, t + 3); eD = emb[(size_t)((t + 7 < TT) ? t + 7 : TT - 1) * KK + j];
    }
    for (; t < len; ++t) {   // tail 0-3 steps
        VSTEP(eA, t);
        eA = eB; eB = eC; eC = eD;
    }

    score += endT[j];
    // one-time first-index argmax over lanes
    float bm = -__builtin_inff();
    int bt = 0;
#pragma unroll
    for (int i = 0; i < KK; ++i) {
        const float si = RLANE(i);
        if (si > bm) { bm = si; bt = i; }
    }
    if (j == 0) btarr[b] = bt;
}

// ---------------- hist recompute: massively parallel (validated r8-r10) ----------------
__global__ __launch_bounds__(256)
void hist_kernel(const float* __restrict__ em, const void* __restrict__ maskp,
                 const float* __restrict__ trans, const float* __restrict__ shist,
                 uchar* __restrict__ histg)
{
    const int tid = threadIdx.x;
    const int bid = blockIdx.x;
    const int b = bid >> 6;
    const int t0 = (bid & 63) * 8;

    __shared__ float tl[64][65];
    __shared__ float srow[8][64];

    const uchar* m8 = (const uchar*)maskp;
    const int* m32 = (const int*)maskp;
    const bool u8m = (m8[1] != 0);

#pragma unroll
    for (int p = 0; p < 16; ++p) {
        const int idx = p * 256 + tid;
        tl[idx >> 6][idx & 63] = trans[idx];
    }
#pragma unroll
    for (int p = 0; p < 2; ++p) {
        const int idx = p * 256 + tid;
        const int r = idx >> 6, i2 = idx & 63;
        const int ts = t0 - 1 + r;
        srow[r][i2] = (ts >= 0) ? shist[((size_t)b * TT + ts) * KK + i2] : 0.f;
    }
    __syncthreads();

    const int j = tid & 63;
    const int tq = tid >> 6;

#pragma unroll
    for (int half = 0; half < 2; ++half) {
        const int toff = tq * 2 + half;
        const int t = t0 + toff;
        if (t == 0) continue;
        const int mt = u8m ? (int)m8[b * TT + t] : m32[b * TT + t];
        uchar hv;
        if (!mt) {
            hv = (uchar)j;
        } else {
            const float e = em[((size_t)b * TT + t) * KK + j];
            const float* sr = &srow[toff][0];
            float bm = -__builtin_inff();
            int bi = 0;
#pragma unroll 16
            for (int i = 0; i < KK; ++i) {
                const float cand = (sr[i] + tl[i][j]) + e;   // reference order
                if (cand > bm) { bm = cand; bi = i; }        // strict >: first index
            }
            hv = (uchar)bi;
        }
        histg[((size_t)b * TT + t) * KK + j] = hv;
    }
}

// ---------------- Backtrack (validated r8-r10) ----------------
__global__ __launch_bounds__(256)
void viterbi_bt(const uchar* __restrict__ histg, const int* __restrict__ btarr,
                float* __restrict__ pred)
{
    const int b = blockIdx.x;
    const int tid = threadIdx.x;
    const int w = tid >> 6;
    const int j = tid & 63;

    __shared__ uchar hist[TT][KK];
    __shared__ uchar hypo[8][64][64];

    const uint4* src = (const uint4*)(histg + (size_t)b * TT * KK);
    uint4* dst = (uint4*)&hist[0][0];
#pragma unroll
    for (int p = 0; p < 8; ++p) dst[p * 256 + tid] = src[p * 256 + tid];
    __syncthreads();

    const int bt = btarr[b];

#pragma unroll
    for (int ss = 0; ss < 2; ++ss) {
        const int s = w * 2 + ss;
        int tag = j;
        if (s == 7) {
            hypo[7][63][j] = (uchar)j;
            for (int t = TT - 1; t >= 7 * 64 + 1; --t) {
                tag = hist[t][tag];
                hypo[7][t - 1 - 7 * 64][j] = (uchar)tag;
            }
        } else {
            for (int t = (s + 1) * 64; t >= s * 64 + 1; --t) {
                tag = hist[t][tag];
                hypo[s][t - 1 - s * 64][j] = (uchar)tag;
            }
        }
    }
    __syncthreads();

    int rows_[8];
    rows_[7] = bt;
#pragma unroll
    for (int s = 6; s >= 0; --s) rows_[s] = hypo[s + 1][0][rows_[s + 1]];

    float* pb = pred + (size_t)b * TT;
#pragma unroll
    for (int ss = 0; ss < 2; ++ss) {
        const int s = w * 2 + ss;
        pb[s * 64 + j] = (float)hypo[s][j][rows_[s]];
    }
}

// ---------------- Fallback monolithic viterbi (round-6, proven) ----------------
__global__ __launch_bounds__(256)
void viterbi_kernel(const float* __restrict__ em, const void* __restrict__ maskp,
                    const float* __restrict__ startT, const float* __restrict__ endT,
                    const float* __restrict__ trans, float* __restrict__ pred)
{
    const int b = blockIdx.x;
    const int tid = threadIdx.x;
    const int w = tid >> 6;
    const int j = tid & 63;

    __shared__ uchar hist[TT][KK];
    __shared__ uchar hypo[8][64][64];
    __shared__ int bt_sh;

    const uchar* m8 = (const uchar*)maskp;
    const int* m32 = (const int*)maskp;
    const bool u8m = (m8[1] != 0);

    if (w == 0) {
        float tc[KK];
#pragma unroll
        for (int i = 0; i < KK; ++i) tc[i] = trans[i * KK + j];

        const float* emb = em + (size_t)b * TT * KK;
        float score = startT[j] + emb[j];
        const float endv = endT[j];

        float e_cur = emb[KK + j];
        int   m_cur = u8m ? (int)m8[b * TT + 1] : m32[b * TT + 1];

        int t = 1;
        for (; t < TT; ++t) {
            const int tn2 = (t + 1 < TT) ? (t + 1) : (TT - 1);
            const float e_next = emb[(size_t)tn2 * KK + j];
            const int   m_next = u8m ? (int)m8[b * TT + tn2] : m32[b * TT + tn2];
            if (!m_cur) break;
            float m = -__builtin_inff();
            int idx = 0;
#pragma unroll
            for (int i = 0; i < KK; ++i) {
                const float si = __uint_as_float(__builtin_amdgcn_readlane(__float_as_uint(score), i));
                const float v = (si + tc[i]) + e_cur;
                if (v > m) { m = v; idx = i; }
            }
            score = m;
            hist[t][j] = (uchar)idx;
            e_cur = e_next; m_cur = m_next;
        }
        for (; t < TT; ++t) hist[t][j] = (uchar)j;

        score += endv;
        float bm = -__builtin_inff();
        int bt = 0;
#pragma unroll
        for (int i = 0; i < KK; ++i) {
            const float si = __uint_as_float(__builtin_amdgcn_readlane(__float_as_uint(score), i));
            if (si > bm) { bm = si; bt = i; }
        }
        if (j == 0) bt_sh = bt;
    }
    __syncthreads();

#pragma unroll
    for (int ss = 0; ss < 2; ++ss) {
        const int s = w * 2 + ss;
        int tag = j;
        if (s == 7) {
            hypo[7][63][j] = (uchar)j;
            for (int t = TT - 1; t >= 7 * 64 + 1; --t) {
                tag = hist[t][tag];
                hypo[7][t - 1 - 7 * 64][j] = (uchar)tag;
            }
        } else {
            for (int t = (s + 1) * 64; t >= s * 64 + 1; --t) {
                tag = hist[t][tag];
                hypo[s][t - 1 - s * 64][j] = (uchar)tag;
            }
        }
    }
    __syncthreads();

    const int bt = bt_sh;
    int rows_[8];
    rows_[7] = bt;
#pragma unroll
    for (int s = 6; s >= 0; --s) rows_[s] = hypo[s + 1][0][rows_[s + 1]];

    float* pb = pred + (size_t)b * TT;
#pragma unroll
    for (int ss = 0; ss < 2; ++ss) {
        const int s = w * 2 + ss;
        pb[s * 64 + j] = (float)hypo[s][j][rows_[s]];
    }
}

extern "C" void kernel_launch(void* const* d_in, const int* in_sizes, int n_in,
                              void* d_out, int out_size, void* d_ws, size_t ws_size,
                              hipStream_t stream) {
    const float* X      = (const float*)d_in[0];
    const void*  mask   = d_in[1];
    const float* W      = (const float*)d_in[2];
    const float* bias   = (const float*)d_in[3];
    const float* startT = (const float*)d_in[4];
    const float* endT   = (const float*)d_in[5];
    const float* trans  = (const float*)d_in[6];

    float* em   = (float*)d_out;
    float* pred = (float*)d_out + (size_t)BB * TT * KK;

    emission_kernel<<<(BB * TT) / BM, 256, 0, stream>>>(X, W, bias, em);

    const size_t SH_BYTES = (size_t)BB * TT * KK * sizeof(float);   // 8 MB
    const size_t HI_BYTES = (size_t)BB * TT * KK;                   // 2 MB
    const size_t NEED = SH_BYTES + HI_BYTES + 256;

    if (ws_size >= NEED) {
        float* shist = (float*)d_ws;
        uchar* histg = (uchar*)d_ws + SH_BYTES;
        int*   btarr = (int*)((uchar*)d_ws + SH_BYTES + HI_BYTES);
        viterbi_fwd<<<BB, 64, 0, stream>>>(em, mask, startT, endT, trans, shist, btarr);
        hist_kernel<<<BB * 64, 256, 0, stream>>>(em, mask, trans, shist, histg);
        viterbi_bt<<<BB, 256, 0, stream>>>(histg, btarr, pred);
    } else {
        viterbi_kernel<<<BB, 256, 0, stream>>>(em, mask, startT, endT, trans, pred);
    }
}